// Round 19
// baseline (299.151 us; speedup 1.0000x reference)
//
#include <hip/hip_runtime.h>
#include <float.h>

#define N_TRAIN 50000
#define NBLKS   392          // 128-col shortlist blocks
#define MPAD    1664         // 26*64 padded row count
#define DDIM    384
#define M_ROWS  1568         // 8*196
#define KNN     20
#define K2      24           // candidate-inclusion rank (margin over 20)
#define SELMAX  64
#define NCLS    21
#define CAPBUF  768
#define NENT    1568         // 392*4 shortlist entries per row
#define NGEMM   1274         // 26 mblk x 49 ngrp
#define NTRT    4704         // 784x6 trainT tiles
#define NLAB    3128         // 782x4 label tiles

typedef __attribute__((ext_vector_type(8))) short bf16x8;
typedef __attribute__((ext_vector_type(4))) float f32x4;

#define GLOAD_LDS16(gp, lp) \
  __builtin_amdgcn_global_load_lds((const __attribute__((address_space(1))) void*)(gp), \
                                   (__attribute__((address_space(3))) void*)(lp), 16, 0, 0)

// round-to-nearest-even f32 -> bf16
static __device__ __forceinline__ unsigned short f2bf(float f) {
  unsigned int u = __float_as_uint(f);
  unsigned int r = (u + 0x7fffu + ((u >> 16) & 1u)) >> 16;
  return (unsigned short)r;
}
static __device__ __forceinline__ float bf2f(unsigned short h) {
  return __uint_as_float(((unsigned int)h) << 16);
}
// order-preserving f32 -> u32 key
static __device__ __forceinline__ unsigned int flip32(unsigned int u) {
  return (u & 0x80000000u) ? ~u : (u | 0x80000000u);
}

#define CSW(x, y) { unsigned int _hi = max(x, y); unsigned int _lo = min(x, y); x = _hi; y = _lo; }

// ---------------- prep_ab: Bpack (train) + Apack (test) ----------------------
// flat grid 256-thr: [0,4704) train->Bpack tiles; [4704,7200) Apack
__global__ __launch_bounds__(256) void prep_ab(const float* __restrict__ train,
                                               const float* __restrict__ test,
                                               unsigned short* __restrict__ Bpack,
                                               unsigned short* __restrict__ Apack) {
  __shared__ float tile[64][65];
  const int b = blockIdx.x, t = threadIdx.x;

  if (b < 4704) {
    const int c0 = (b % 784) * 64;   // col base (0..50176)
    const int r0 = (b / 784) * 64;   // k base (0..384)
#pragma unroll
    for (int i = 0; i < 16; ++i) {
      int idx = i * 256 + t;
      int r = idx >> 6, c = idx & 63;
      int cc = c0 + c;
      tile[r][c] = (cc < N_TRAIN) ? train[(size_t)(r0 + r) * N_TRAIN + cc] : 0.f;
    }
    __syncthreads();
    // Bpack: [nt=3136][kc=12][lane=64][8]; B[col=nt*16+(l&15)][k=kc*32+(l>>4)*8+j]
#pragma unroll
    for (int it = 0; it < 2; ++it) {
      int u = it * 256 + t;
      int c = u & 63, koctL = u >> 6;            // koctL 0..7
      int col = c0 + c;
      int koct = (r0 >> 3) + koctL;
      int kc = koct >> 2, l4 = koct & 3;
      int nt = col >> 4, l15 = col & 15;
      size_t base = ((size_t)(nt * 12 + kc) * 64 + l4 * 16 + l15) * 8;
      ushort4 h0, h1;
      h0.x = f2bf(tile[koctL * 8 + 0][c]); h0.y = f2bf(tile[koctL * 8 + 1][c]);
      h0.z = f2bf(tile[koctL * 8 + 2][c]); h0.w = f2bf(tile[koctL * 8 + 3][c]);
      h1.x = f2bf(tile[koctL * 8 + 4][c]); h1.y = f2bf(tile[koctL * 8 + 5][c]);
      h1.z = f2bf(tile[koctL * 8 + 6][c]); h1.w = f2bf(tile[koctL * 8 + 7][c]);
      *(ushort4*)&Bpack[base]     = h0;
      *(ushort4*)&Bpack[base + 4] = h1;
    }
  } else {
    // test -> Apack fragment-major: [mt=104][kc=12][lane=64][8] bf16
    int o = (b - 4704) * 256 + t;              // < 104*12*512 = 638,976 exactly
    int j = o & 7;
    int l = (o >> 3) & 63;
    int kcmt = o >> 9;
    int kc = kcmt % 12, mt = kcmt / 12;
    int row = mt * 16 + (l & 15);
    int k = kc * 32 + (l >> 4) * 8 + j;
    Apack[o] = (row < M_ROWS) ? f2bf(test[(size_t)row * DDIM + k]) : (unsigned short)0;
  }
}

// ---------------- fused_main: 64-row GEMM blocks + trainT + labT -------------
// 512 thr, dynamic LDS 53,248 B, launch_bounds(512,2) -> VGPR cap 128 (the
// r18 run proved co-scheduling works but (512,4)'s 64-VGPR cap starved the
// B-prefetch; 2 blocks/CU is already the LDS limit so nothing is lost).
// [0,1274): gemm; [1274,5978): trainT tiles; [5978,9106): labT tiles.
__global__ __launch_bounds__(512, 2) void fused_main(const unsigned short* __restrict__ Apack,
                                                     const unsigned short* __restrict__ Bpack,
                                                     const float* __restrict__ train,
                                                     const int* __restrict__ labels,
                                                     unsigned int* __restrict__ toplist,
                                                     float* __restrict__ trainT,
                                                     unsigned char* __restrict__ labT) {
  extern __shared__ unsigned short lds16[];   // gemm: A 48KB + bounce 4KB
  const int b = blockIdx.x, t = threadIdx.x;

  if (b >= NGEMM) {
    if (b < NGEMM + NTRT) {
      // ---- trainT: train [384][50000] -> trainT [50000][384] f32 ----
      float* ftile = (float*)lds16;   // [64][65]
      const int i2 = b - NGEMM;
      const int c0 = (i2 % 784) * 64, r0 = (i2 / 784) * 64;
#pragma unroll
      for (int i = 0; i < 8; ++i) {
        int idx = i * 512 + t;
        int r = idx >> 6, c = idx & 63;
        int cc = c0 + c;
        ftile[r * 65 + c] = (cc < N_TRAIN) ? train[(size_t)(r0 + r) * N_TRAIN + cc] : 0.f;
      }
      __syncthreads();
#pragma unroll
      for (int i = 0; i < 8; ++i) {
        int idx = i * 512 + t;
        int c = idx >> 6, r = idx & 63;
        int cc = c0 + c;
        if (cc < N_TRAIN) trainT[(size_t)cc * DDIM + r0 + r] = ftile[r * 65 + c];
      }
    } else {
      // ---- labT: labels [256][50000] i32 -> labT [50000][256] u8 ----
      unsigned int* itile = (unsigned int*)lds16;   // [64][65]
      const int i3 = b - NGEMM - NTRT;
      const int c0 = (i3 % 782) * 64, r0 = (i3 / 782) * 64;
#pragma unroll
      for (int i = 0; i < 8; ++i) {
        int idx = i * 512 + t;
        int r = idx >> 6, c = idx & 63;
        int cc = c0 + c;
        itile[r * 65 + c] = (cc < N_TRAIN) ? (unsigned int)labels[(size_t)(r0 + r) * N_TRAIN + cc] : 0u;
      }
      __syncthreads();
#pragma unroll
      for (int i = 0; i < 8; ++i) {
        int idx = i * 512 + t;
        int c = idx >> 6, r = idx & 63;
        int cc = c0 + c;
        if (cc < N_TRAIN) labT[(size_t)cc * 256 + r0 + r] = (unsigned char)itile[r * 65 + c];
      }
    }
    return;
  }

  // ---- gemm: 64 rows x (2 steps x 512 cols), 8 waves 2x4 (wave 32x128) ----
  uint4* bounce = (uint4*)((char*)lds16 + 49152);   // [64 rows][4 wc]

  // bijective XCD chunking: nwg = 1274 = 2*160 + 6*159
  const int xcd = b & 7, jj = b >> 3;
  const int wg = (xcd < 2 ? xcd * 160 : 320 + (xcd - 2) * 159) + jj;
  const int mblk = wg % 26, ngrp = wg / 26;   // 26 consecutive wg share ngrp (B L2-local)
  const int m0 = mblk * 64;

  const int wid = t >> 6, lane = t & 63;
  const int wr = wid >> 2, wc = wid & 3;      // 2 x 4 waves; wave = 32 rows x 128 cols
  const int l15 = lane & 15, l4 = lane >> 4;

  // stage A once: 48KB linear copy of Apack block region (4 mt units)
  const unsigned short* Asrc = Apack + (size_t)(mblk * 4) * 12 * 512;
#pragma unroll
  for (int j = 0; j < 6; ++j)
    GLOAD_LDS16(Asrc + (size_t)j * 4096 + wid * 512 + lane * 8,
                &lds16[j * 4096 + wid * 512]);
  __syncthreads();   // drains vmcnt before barrier

#pragma unroll 1
  for (int s = 0; s < 2; ++s) {
    const int colbase = ngrp * 1024 + s * 512;
    const unsigned short* Bb = Bpack + (size_t)(colbase / 16 + wc * 8) * 12 * 512;

    f32x4 acc[2][8];
    const f32x4 zero = {0.f, 0.f, 0.f, 0.f};
#pragma unroll
    for (int f = 0; f < 2; ++f)
#pragma unroll
      for (int n = 0; n < 8; ++n) acc[f][n] = zero;

#pragma unroll 2
    for (int kc = 0; kc < 12; ++kc) {
      bf16x8 a[2], bv[8];
#pragma unroll
      for (int n = 0; n < 8; ++n)
        bv[n] = *(const bf16x8*)&Bb[((size_t)(n * 12 + kc) * 64 + lane) * 8];
#pragma unroll
      for (int f = 0; f < 2; ++f)
        a[f] = *(const bf16x8*)&lds16[((wr * 2 + f) * 12 + kc) * 512 + lane * 8];
      __builtin_amdgcn_s_setprio(1);
#pragma unroll
      for (int f = 0; f < 2; ++f)
#pragma unroll
        for (int n = 0; n < 8; ++n)
          acc[f][n] = __builtin_amdgcn_mfma_f32_16x16x32_bf16(a[f], bv[n], acc[f][n], 0, 0, 0);
      __builtin_amdgcn_s_setprio(0);
    }

    // epilogue: wave-private top-4 of its 128 cols, per row
#pragma unroll
    for (int f = 0; f < 2; ++f) {
#pragma unroll
      for (int r = 0; r < 4; ++r) {
        unsigned int e[8];
#pragma unroll
        for (int n = 0; n < 8; ++n) {
          int col = colbase + wc * 128 + n * 16 + l15;
          unsigned int k16 = flip32(__float_as_uint(acc[f][n][r])) >> 16;
          e[n] = (col < N_TRAIN) ? ((k16 << 16) | (0xFFFFu - (unsigned int)col)) : 0u;
        }
        // top-4 of 8 in-lane
        CSW(e[0], e[1]); CSW(e[2], e[3]); CSW(e[0], e[2]); CSW(e[1], e[3]); CSW(e[1], e[2]);
        CSW(e[4], e[5]); CSW(e[6], e[7]); CSW(e[4], e[6]); CSW(e[5], e[7]); CSW(e[5], e[6]);
        unsigned int v0 = max(e[0], e[7]), v1 = max(e[1], e[6]);
        unsigned int v2 = max(e[2], e[5]), v3 = max(e[3], e[4]);
        CSW(v0, v2); CSW(v1, v3); CSW(v0, v1); CSW(v2, v3);
        // butterfly merge across the 16 l15-lanes
#pragma unroll
        for (int st = 1; st <= 8; st <<= 1) {
          unsigned int p0 = (unsigned int)__shfl_xor((int)v0, st);
          unsigned int p1 = (unsigned int)__shfl_xor((int)v1, st);
          unsigned int p2 = (unsigned int)__shfl_xor((int)v2, st);
          unsigned int p3 = (unsigned int)__shfl_xor((int)v3, st);
          unsigned int t0 = max(v0, p3), t1 = max(v1, p2);
          unsigned int t2 = max(v2, p1), t3 = max(v3, p0);
          CSW(t0, t2); CSW(t1, t3); CSW(t0, t1); CSW(t2, t3);
          v0 = t0; v1 = t1; v2 = t2; v3 = t3;
        }
        if (l15 == 0) {
          uint4 w; w.x = v0; w.y = v1; w.z = v2; w.w = v3;
          bounce[(wr * 32 + f * 16 + l4 * 4 + r) * 4 + wc] = w;
        }
      }
    }
    __syncthreads();

    // coalesced shortlist writeout: [row][blk*4..+3]
    if (t < 256) {
      int row = t >> 2, e = t & 3;
      int grow = m0 + row;
      if (grow < M_ROWS) {
        uint4 w = bounce[row * 4 + e];
        int blk = ngrp * 8 + s * 4 + e;
        *(uint4*)&toplist[(size_t)grow * NENT + blk * 4] = w;
      }
    }
    __syncthreads();   // bounce reused next step
  }
}

// --------- fused tail: shortlist select (+rare rescan) -> f64 refine -> vote --
__global__ __launch_bounds__(256) void tail_fused(const unsigned int* __restrict__ toplist,
                                                  const float* __restrict__ test,
                                                  const float* __restrict__ trainT,
                                                  const unsigned char* __restrict__ labT,
                                                  int* __restrict__ out) {
  const int t = threadIdx.x, m = blockIdx.x;
  __shared__ unsigned int ent[NENT];
  __shared__ unsigned int smax[256];
  __shared__ unsigned int sbuf[CAPBUF];
  __shared__ unsigned int scnt, sTauA, sE24, ccnt2;
  __shared__ unsigned char flg[NBLKS];
  __shared__ short flist[64];
  __shared__ int fcnt, sC2;
  __shared__ unsigned int cbuf[128];
  __shared__ int    selC[SELMAX];
  __shared__ double rvs[SELMAX];
  __shared__ double sv2[SELMAX];
  __shared__ int    si2[SELMAX];
  __shared__ double earr[KNN];
  __shared__ double wv[KNN];
  __shared__ int    wi[KNN];

  if (t == 0) { scnt = 0u; fcnt = 0; ccnt2 = 0u; sC2 = 0; }
  for (int i = t; i < NENT; i += 256) ent[i] = toplist[(size_t)m * NENT + i];
  __syncthreads();

  // tauA = 24th largest of per-thread maxima (ties by tid)
  unsigned int mx = 0u;
  for (int i = t; i < NENT; i += 256) mx = max(mx, ent[i]);
  smax[t] = mx;
  __syncthreads();
  {
    int rnk = 0;
    for (int j = 0; j < 256; ++j)
      rnk += (smax[j] > mx || (smax[j] == mx && j < t)) ? 1 : 0;
    if (rnk == K2 - 1) sTauA = mx;
  }
  __syncthreads();
  const unsigned int tauA = sTauA;

  // collect entries >= tauA; find e24 = 24th-largest entry (u32 unique)
  for (int i = t; i < NENT; i += 256) {
    unsigned int e = ent[i];
    if (e >= tauA) { unsigned int p = atomicAdd(&scnt, 1u); if (p < CAPBUF) sbuf[p] = e; }
  }
  __syncthreads();
  const int C = (int)min(scnt, (unsigned int)CAPBUF);
  for (int s = t; s < C; s += 256) {
    unsigned int e = sbuf[s];
    int rk = 0;
    for (int j = 0; j < C; ++j) rk += (sbuf[j] > e) ? 1 : 0;
    if (rk == K2 - 1) sE24 = e;
  }
  __syncthreads();
  const unsigned int k24 = sE24 >> 16;

  // flag blocks whose 4th shortlist key >= k24
  for (int i = t; i < NBLKS; i += 256) {
    bool fl = (ent[i * 4 + 3] >> 16) >= k24;
    flg[i] = fl ? 1 : 0;
    if (fl) { int p = atomicAdd(&fcnt, 1); if (p < 64) flist[p] = (short)i; }
  }
  __syncthreads();

  // candidates: non-flagged shortlist entries with key >= k24
  for (int i = t; i < NENT; i += 256) {
    unsigned int e = ent[i];
    if ((e >> 16) >= k24) {
      int col = 0xFFFF - (int)(e & 0xFFFFu);
      if (!flg[col >> 7]) { unsigned int p = atomicAdd(&ccnt2, 1u); if (p < 128) cbuf[p] = e; }
    }
  }
  __syncthreads();

  // rescan flagged blocks fully (bf16-rounded f32 dot; 1-ulp slack on key)
  const int FC = min(fcnt, 64);
  for (int q = 0; q < FC; ++q) {
    const int fb = flist[q];
    const int col = fb * 128 + t;
    if (t < 128 && col < N_TRAIN) {
      const float* Tc = trainT + (size_t)col * DDIM;
      const float* Tr = test + (size_t)m * DDIM;
      float s0 = 0.f;
      for (int k = 0; k < DDIM; ++k)
        s0 = fmaf(bf2f(f2bf(Tr[k])), bf2f(f2bf(Tc[k])), s0);
      unsigned int key = flip32(__float_as_uint(s0)) >> 16;
      if (key + 1u >= k24) {
        unsigned int e = (key << 16) | (0xFFFFu - (unsigned int)col);
        unsigned int p = atomicAdd(&ccnt2, 1u);
        if (p < 128) cbuf[p] = e;
      }
    }
  }
  __syncthreads();
  const int CC = (int)min(ccnt2, 128u);

  // rank-select candidates by (key desc, col asc) == u32 desc -> selC[0..C2)
  for (int s = t; s < CC; s += 256) {
    unsigned int e = cbuf[s];
    int rk = 0;
    for (int j = 0; j < CC; ++j) rk += (cbuf[j] > e) ? 1 : 0;
    if (rk < SELMAX) {
      selC[rk] = 0xFFFF - (int)(e & 0xFFFFu);
      atomicMax(&sC2, rk + 1);
    }
  }
  __syncthreads();
  const int C2 = sC2 < SELMAX ? sC2 : SELMAX;   // >= 20 guaranteed

  // ---- f64 refine of C2 cands (4 waves split cands, lanes over d) ----
  const int wid = t >> 6, lane = t & 63;
  float tr[DDIM / 64];
#pragma unroll
  for (int dd = 0; dd < DDIM / 64; ++dd)
    tr[dd] = test[(size_t)m * DDIM + dd * 64 + lane];
#pragma unroll 1
  for (int c = wid; c < C2; c += 4) {
    const float* Tc = trainT + (size_t)selC[c] * DDIM;
    double s = 0.0;
#pragma unroll
    for (int dd = 0; dd < DDIM / 64; ++dd)
      s += (double)tr[dd] * (double)Tc[dd * 64 + lane];
#pragma unroll
    for (int off = 32; off > 0; off >>= 1) s += __shfl_xor(s, off);
    if (lane == 0) rvs[c] = s;
  }
  __syncthreads();

  if (t < C2) {
    double v = rvs[t]; int id = selC[t];
    int r = 0;
    for (int n = 0; n < C2; ++n)
      r += (rvs[n] > v || (rvs[n] == v && selC[n] < id)) ? 1 : 0;
    sv2[r] = v; si2[r] = id;
  }
  __syncthreads();

  if (t < KNN) earr[t] = exp(sv2[t] - sv2[0]);
  __syncthreads();
  if (t < KNN) {
    double ssum = 0.0;
    for (int k = 0; k < KNN; ++k) ssum += earr[k];
    wv[t] = earr[t] / ssum;
    wi[t] = si2[t];
  }
  __syncthreads();

  // ---- per-pixel weighted vote (f64) + argmax ----
  unsigned int packed[5];
#pragma unroll
  for (int q = 0; q < 5; ++q) {
    unsigned int p = 0;
#pragma unroll
    for (int j = 0; j < 4; ++j)
      p |= (unsigned int)labT[(size_t)wi[q * 4 + j] * 256 + t] << (8 * j);
    packed[q] = p;
  }
  double best = -1.0; int bc = 0;
#pragma unroll 1
  for (int c = 0; c < NCLS; ++c) {
    double s = 0.0;
#pragma unroll
    for (int k = 0; k < KNN; ++k) {
      unsigned int lab = (packed[k >> 2] >> ((k & 3) * 8)) & 255u;
      s += (lab == (unsigned int)c) ? wv[k] : 0.0;
    }
    if (s > best) { best = s; bc = c; }
  }
  const int b = m / 196, p = m % 196;
  const int py = p / 14, px = p % 14;
  const int i = t >> 4, j = t & 15;
  out[((size_t)b * 224 + py * 16 + i) * 224 + px * 16 + j] = bc;
}

// ---------------- launch ------------------------------------------------------
// ws layout (bytes), total 139,247,616 (< ~307 MB poisoned ws):
//   labT    @ 0           : 12,800,000
//   Apack   @ 12,800,000  :  1,277,952  (u16 [104][12][64][8])
//   Bpack   @ 14,077,952  : 38,535,168  (u16 [3136][12][64][8])
//   trainT  @ 52,613,120  : 76,800,000  (f32 [50000][384])
//   toplist @ 129,413,120 :  9,834,496  (u32 [1568][1568])
extern "C" void kernel_launch(void* const* d_in, const int* in_sizes, int n_in,
                              void* d_out, int out_size, void* d_ws, size_t ws_size,
                              hipStream_t stream) {
  const float* test  = (const float*)d_in[0];   // [1568][384]
  const float* train = (const float*)d_in[1];   // [384][50000]
  const int* labels  = (const int*)d_in[2];     // [256][50000]
  int* out = (int*)d_out;
  char* ws = (char*)d_ws;

  unsigned char*  labT    = (unsigned char*)ws;
  unsigned short* Apack   = (unsigned short*)(ws + 12800000);
  unsigned short* Bpack   = (unsigned short*)(ws + 14077952);
  float*          trainT  = (float*)(ws + 52613120);
  unsigned int*   toplist = (unsigned int*)(ws + 129413120);

  prep_ab<<<dim3(7200), 256, 0, stream>>>(train, test, Bpack, Apack);
  fused_main<<<dim3(NGEMM + NTRT + NLAB), 512, 53248, stream>>>(
      Apack, Bpack, train, labels, toplist, trainT, labT);
  tail_fused<<<dim3(M_ROWS), 256, 0, stream>>>(toplist, test, trainT, labT, out);
}

// Round 20
// 225.362 us; speedup vs baseline: 1.3274x; 1.3274x over previous
//
#include <hip/hip_runtime.h>
#include <float.h>

#define N_TRAIN 50000
#define NBLKS   392          // 128-col shortlist blocks
#define MPAD    1664         // 13*128 padded row count
#define DDIM    384
#define M_ROWS  1568         // 8*196
#define KNN     20
#define K2      24           // candidate-inclusion rank (margin over 20)
#define SELMAX  64
#define NCLS    21
#define CAPBUF  768
#define NENT    1568         // 392*4 shortlist entries per row

typedef __attribute__((ext_vector_type(8))) short bf16x8;
typedef __attribute__((ext_vector_type(4))) float f32x4;

#define GLOAD_LDS16(gp, lp) \
  __builtin_amdgcn_global_load_lds((const __attribute__((address_space(1))) void*)(gp), \
                                   (__attribute__((address_space(3))) void*)(lp), 16, 0, 0)

// round-to-nearest-even f32 -> bf16
static __device__ __forceinline__ unsigned short f2bf(float f) {
  unsigned int u = __float_as_uint(f);
  unsigned int r = (u + 0x7fffu + ((u >> 16) & 1u)) >> 16;
  return (unsigned short)r;
}
static __device__ __forceinline__ float bf2f(unsigned short h) {
  return __uint_as_float(((unsigned int)h) << 16);
}
// order-preserving f32 -> u32 key
static __device__ __forceinline__ unsigned int flip32(unsigned int u) {
  return (u & 0x80000000u) ? ~u : (u | 0x80000000u);
}

#define CSW(x, y) { unsigned int _hi = max(x, y); unsigned int _lo = min(x, y); x = _hi; y = _lo; }

// ---------------- fused prep: labels-T | train-T+Bpack | Apack ---------------
// flat grid: [0,3128) labels 782x4; [3128,7832) train 784x6; [7832,10328) Apack
__global__ __launch_bounds__(256) void prep_fused(const int* __restrict__ labels,
                                                  const float* __restrict__ train,
                                                  const float* __restrict__ test,
                                                  unsigned char* __restrict__ labT,
                                                  unsigned short* __restrict__ Bpack,
                                                  float* __restrict__ trainT,
                                                  unsigned short* __restrict__ Apack) {
  __shared__ unsigned int tile[64][65];
  const int b = blockIdx.x, t = threadIdx.x;

  if (b < 3128) {
    // ---- labels [256][50000] i32 -> labT [50000][256] u8 ----
    const int c0 = (b % 782) * 64, r0 = (b / 782) * 64;
#pragma unroll
    for (int i = 0; i < 16; ++i) {
      int idx = i * 256 + t;
      int r = idx >> 6, c = idx & 63;
      int cc = c0 + c;
      tile[r][c] = (cc < N_TRAIN) ? (unsigned int)labels[(size_t)(r0 + r) * N_TRAIN + cc] : 0u;
    }
    __syncthreads();
#pragma unroll
    for (int i = 0; i < 16; ++i) {
      int idx = i * 256 + t;
      int c = idx >> 6, r = idx & 63;
      int cc = c0 + c;
      if (cc < N_TRAIN) labT[(size_t)cc * 256 + r0 + r] = (unsigned char)tile[r][c];
    }
  } else if (b < 7832) {
    // ---- train [384][50000] f32 -> Bpack frag-major bf16 + trainT f32 ----
    const int i2 = b - 3128;
    const int c0 = (i2 % 784) * 64;   // col base (0..50176)
    const int r0 = (i2 / 784) * 64;   // k base (0..384)
#pragma unroll
    for (int i = 0; i < 16; ++i) {
      int idx = i * 256 + t;
      int r = idx >> 6, c = idx & 63;
      int cc = c0 + c;
      float v = (cc < N_TRAIN) ? train[(size_t)(r0 + r) * N_TRAIN + cc] : 0.f;
      tile[r][c] = __float_as_uint(v);
    }
    __syncthreads();
    // Bpack: [nt=3136][kc=12][lane=64][8]; B[col=nt*16+(l&15)][k=kc*32+(l>>4)*8+j]
#pragma unroll
    for (int it = 0; it < 2; ++it) {
      int u = it * 256 + t;
      int c = u & 63, koctL = u >> 6;            // koctL 0..7
      int col = c0 + c;
      int koct = (r0 >> 3) + koctL;
      int kc = koct >> 2, l4 = koct & 3;
      int nt = col >> 4, l15 = col & 15;
      size_t base = ((size_t)(nt * 12 + kc) * 64 + l4 * 16 + l15) * 8;
      ushort4 h0, h1;
      h0.x = f2bf(__uint_as_float(tile[koctL * 8 + 0][c]));
      h0.y = f2bf(__uint_as_float(tile[koctL * 8 + 1][c]));
      h0.z = f2bf(__uint_as_float(tile[koctL * 8 + 2][c]));
      h0.w = f2bf(__uint_as_float(tile[koctL * 8 + 3][c]));
      h1.x = f2bf(__uint_as_float(tile[koctL * 8 + 4][c]));
      h1.y = f2bf(__uint_as_float(tile[koctL * 8 + 5][c]));
      h1.z = f2bf(__uint_as_float(tile[koctL * 8 + 6][c]));
      h1.w = f2bf(__uint_as_float(tile[koctL * 8 + 7][c]));
      *(ushort4*)&Bpack[base]     = h0;
      *(ushort4*)&Bpack[base + 4] = h1;
    }
#pragma unroll
    for (int i = 0; i < 16; ++i) {
      int idx = i * 256 + t;
      int c = idx >> 6, r = idx & 63;
      int cc = c0 + c;
      if (cc < N_TRAIN) trainT[(size_t)cc * DDIM + r0 + r] = __uint_as_float(tile[r][c]);
    }
  } else {
    // ---- test -> Apack fragment-major: [mt=104][kc=12][lane=64][8] bf16 ----
    int o = (b - 7832) * 256 + t;              // < 104*12*512 = 638,976 exactly
    int j = o & 7;
    int l = (o >> 3) & 63;
    int kcmt = o >> 9;
    int kc = kcmt % 12, mt = kcmt / 12;
    int row = mt * 16 + (l & 15);
    int k = kc * 32 + (l >> 4) * 8 + j;
    Apack[o] = (row < M_ROWS) ? f2bf(test[(size_t)row * DDIM + k]) : (unsigned short)0;
  }
}

// ---------------- MFMA GEMM: A-in-LDS (once per block), B reg-streamed --------
// Block: 128 rows x (2 steps x 512 cols), 8 waves 2x4 (wave 64x128).
// A tile 128x384 bf16 = 96KB LDS, staged once via global_load_lds; ZERO
// main-loop barriers. Epilogue: wave-private top-4 per 128-col block.
__global__ __launch_bounds__(512, 2) void mfma_gemm(const unsigned short* __restrict__ Apack,
                                                    const unsigned short* __restrict__ Bpack,
                                                    unsigned int* __restrict__ toplist) {
  extern __shared__ unsigned short lds16[];   // A: u16[49152] (96KB); bounce @98304B
  uint4* bounce = (uint4*)((char*)lds16 + 98304);   // [128 rows][4 wc]
  const int t = threadIdx.x;

  // bijective XCD chunking: nwg = 637 = 8*79 + 5
  const int flat = blockIdx.x;
  const int xcd = flat & 7, jj = flat >> 3;
  const int wg = (xcd < 5 ? xcd * 80 : 400 + (xcd - 5) * 79) + jj;
  const int mblk = wg % 13, ngrp = wg / 13;   // 13 consecutive wg share ngrp (B L2-local)
  const int m0 = mblk * 128;

  const int wid = t >> 6, lane = t & 63;
  const int wr = wid >> 2, wc = wid & 3;      // 2 x 4 waves; wave = 64 rows x 128 cols
  const int l15 = lane & 15, l4 = lane >> 4;

  // ---- stage A once: 96KB linear copy of Apack block region ----
  const unsigned short* Asrc = Apack + (size_t)(mblk * 8) * 12 * 512;
#pragma unroll
  for (int j = 0; j < 12; ++j)
    GLOAD_LDS16(Asrc + (size_t)j * 4096 + wid * 512 + lane * 8,
                &lds16[j * 4096 + wid * 512]);
  __syncthreads();   // compiler drains vmcnt before barrier

#pragma unroll 1
  for (int s = 0; s < 2; ++s) {
    const int colbase = ngrp * 1024 + s * 512;
    const unsigned short* Bb = Bpack + (size_t)(colbase / 16 + wc * 8) * 12 * 512;

    f32x4 acc[4][8];
    const f32x4 zero = {0.f, 0.f, 0.f, 0.f};
#pragma unroll
    for (int f = 0; f < 4; ++f)
#pragma unroll
      for (int n = 0; n < 8; ++n) acc[f][n] = zero;

#pragma unroll 2
    for (int kc = 0; kc < 12; ++kc) {
      bf16x8 a[4], b[8];
#pragma unroll
      for (int n = 0; n < 8; ++n)
        b[n] = *(const bf16x8*)&Bb[((size_t)(n * 12 + kc) * 64 + lane) * 8];
#pragma unroll
      for (int f = 0; f < 4; ++f)
        a[f] = *(const bf16x8*)&lds16[((wr * 4 + f) * 12 + kc) * 512 + lane * 8];
      __builtin_amdgcn_s_setprio(1);
#pragma unroll
      for (int f = 0; f < 4; ++f)
#pragma unroll
        for (int n = 0; n < 8; ++n)
          acc[f][n] = __builtin_amdgcn_mfma_f32_16x16x32_bf16(a[f], b[n], acc[f][n], 0, 0, 0);
      __builtin_amdgcn_s_setprio(0);
    }

    // ---- epilogue: wave-private top-4 of its 128 cols, per row ----
#pragma unroll
    for (int f = 0; f < 4; ++f) {
#pragma unroll
      for (int r = 0; r < 4; ++r) {
        unsigned int e[8];
#pragma unroll
        for (int n = 0; n < 8; ++n) {
          int col = colbase + wc * 128 + n * 16 + l15;
          unsigned int k16 = flip32(__float_as_uint(acc[f][n][r])) >> 16;
          e[n] = (col < N_TRAIN) ? ((k16 << 16) | (0xFFFFu - (unsigned int)col)) : 0u;
        }
        // top-4 of 8 in-lane: sort4 + sort4 + bitonic clean + sort4
        CSW(e[0], e[1]); CSW(e[2], e[3]); CSW(e[0], e[2]); CSW(e[1], e[3]); CSW(e[1], e[2]);
        CSW(e[4], e[5]); CSW(e[6], e[7]); CSW(e[4], e[6]); CSW(e[5], e[7]); CSW(e[5], e[6]);
        unsigned int v0 = max(e[0], e[7]), v1 = max(e[1], e[6]);
        unsigned int v2 = max(e[2], e[5]), v3 = max(e[3], e[4]);
        CSW(v0, v2); CSW(v1, v3); CSW(v0, v1); CSW(v2, v3);
        // butterfly merge across the 16 l15-lanes (strides 1,2,4,8)
#pragma unroll
        for (int st = 1; st <= 8; st <<= 1) {
          unsigned int p0 = (unsigned int)__shfl_xor((int)v0, st);
          unsigned int p1 = (unsigned int)__shfl_xor((int)v1, st);
          unsigned int p2 = (unsigned int)__shfl_xor((int)v2, st);
          unsigned int p3 = (unsigned int)__shfl_xor((int)v3, st);
          unsigned int t0 = max(v0, p3), t1 = max(v1, p2);
          unsigned int t2 = max(v2, p1), t3 = max(v3, p0);
          CSW(t0, t2); CSW(t1, t3); CSW(t0, t1); CSW(t2, t3);
          v0 = t0; v1 = t1; v2 = t2; v3 = t3;
        }
        if (l15 == 0) {
          uint4 w; w.x = v0; w.y = v1; w.z = v2; w.w = v3;
          bounce[(wr * 64 + f * 16 + l4 * 4 + r) * 4 + wc] = w;
        }
      }
    }
    __syncthreads();

    // ---- coalesced shortlist writeout: [row][blk*4..+3] ----
    {
      int row = t >> 2, e = t & 3;
      int grow = m0 + row;
      if (grow < M_ROWS) {
        uint4 w = bounce[row * 4 + e];
        int blk = ngrp * 8 + s * 4 + e;
        *(uint4*)&toplist[(size_t)grow * NENT + blk * 4] = w;
      }
    }
    __syncthreads();   // bounce reused next step
  }
}

// --------- fused tail: shortlist select (+rare rescan) -> f64 refine -> vote --
__global__ __launch_bounds__(256) void tail_fused(const unsigned int* __restrict__ toplist,
                                                  const float* __restrict__ test,
                                                  const float* __restrict__ trainT,
                                                  const unsigned char* __restrict__ labT,
                                                  int* __restrict__ out) {
  const int t = threadIdx.x, m = blockIdx.x;
  __shared__ unsigned int ent[NENT];
  __shared__ unsigned int smax[256];
  __shared__ unsigned int sbuf[CAPBUF];
  __shared__ unsigned int scnt, sTauA, sE24, ccnt2;
  __shared__ unsigned char flg[NBLKS];
  __shared__ short flist[64];
  __shared__ int fcnt, sC2;
  __shared__ unsigned int cbuf[128];
  __shared__ int    selC[SELMAX];
  __shared__ double rvs[SELMAX];
  __shared__ double sv2[SELMAX];
  __shared__ int    si2[SELMAX];
  __shared__ double earr[KNN];
  __shared__ double wv[KNN];
  __shared__ int    wi[KNN];

  if (t == 0) { scnt = 0u; fcnt = 0; ccnt2 = 0u; sC2 = 0; }
  for (int i = t; i < NENT; i += 256) ent[i] = toplist[(size_t)m * NENT + i];
  __syncthreads();

  // tauA = 24th largest of per-thread maxima (ties by tid)
  unsigned int mx = 0u;
  for (int i = t; i < NENT; i += 256) mx = max(mx, ent[i]);
  smax[t] = mx;
  __syncthreads();
  {
    int rnk = 0;
    for (int j = 0; j < 256; ++j)
      rnk += (smax[j] > mx || (smax[j] == mx && j < t)) ? 1 : 0;
    if (rnk == K2 - 1) sTauA = mx;
  }
  __syncthreads();
  const unsigned int tauA = sTauA;

  // collect entries >= tauA; find e24 = 24th-largest entry (u32 unique)
  for (int i = t; i < NENT; i += 256) {
    unsigned int e = ent[i];
    if (e >= tauA) { unsigned int p = atomicAdd(&scnt, 1u); if (p < CAPBUF) sbuf[p] = e; }
  }
  __syncthreads();
  const int C = (int)min(scnt, (unsigned int)CAPBUF);
  for (int s = t; s < C; s += 256) {
    unsigned int e = sbuf[s];
    int rk = 0;
    for (int j = 0; j < C; ++j) rk += (sbuf[j] > e) ? 1 : 0;
    if (rk == K2 - 1) sE24 = e;
  }
  __syncthreads();
  const unsigned int k24 = sE24 >> 16;

  // flag blocks whose 4th shortlist key >= k24 (may hide >4 elems above k24)
  for (int i = t; i < NBLKS; i += 256) {
    bool fl = (ent[i * 4 + 3] >> 16) >= k24;
    flg[i] = fl ? 1 : 0;
    if (fl) { int p = atomicAdd(&fcnt, 1); if (p < 64) flist[p] = (short)i; }
  }
  __syncthreads();

  // candidates: non-flagged shortlist entries with key >= k24
  for (int i = t; i < NENT; i += 256) {
    unsigned int e = ent[i];
    if ((e >> 16) >= k24) {
      int col = 0xFFFF - (int)(e & 0xFFFFu);
      if (!flg[col >> 7]) { unsigned int p = atomicAdd(&ccnt2, 1u); if (p < 128) cbuf[p] = e; }
    }
  }
  __syncthreads();

  // rescan flagged blocks fully (bf16-rounded f32 dot; 1-ulp slack on key)
  const int FC = min(fcnt, 64);
  for (int q = 0; q < FC; ++q) {
    const int fb = flist[q];
    const int col = fb * 128 + t;
    if (t < 128 && col < N_TRAIN) {
      const float* Tc = trainT + (size_t)col * DDIM;
      const float* Tr = test + (size_t)m * DDIM;
      float s0 = 0.f;
      for (int k = 0; k < DDIM; ++k)
        s0 = fmaf(bf2f(f2bf(Tr[k])), bf2f(f2bf(Tc[k])), s0);
      unsigned int key = flip32(__float_as_uint(s0)) >> 16;
      if (key + 1u >= k24) {
        unsigned int e = (key << 16) | (0xFFFFu - (unsigned int)col);
        unsigned int p = atomicAdd(&ccnt2, 1u);
        if (p < 128) cbuf[p] = e;
      }
    }
  }
  __syncthreads();
  const int CC = (int)min(ccnt2, 128u);

  // rank-select candidates by (key desc, col asc) == u32 desc -> selC[0..C2)
  for (int s = t; s < CC; s += 256) {
    unsigned int e = cbuf[s];
    int rk = 0;
    for (int j = 0; j < CC; ++j) rk += (cbuf[j] > e) ? 1 : 0;
    if (rk < SELMAX) {
      selC[rk] = 0xFFFF - (int)(e & 0xFFFFu);
      atomicMax(&sC2, rk + 1);
    }
  }
  __syncthreads();
  const int C2 = sC2 < SELMAX ? sC2 : SELMAX;   // >= 20 guaranteed (>=24 cands)

  // ---- f64 refine of C2 cands (4 waves split cands, lanes over d) ----
  const int wid = t >> 6, lane = t & 63;
  float tr[DDIM / 64];
#pragma unroll
  for (int dd = 0; dd < DDIM / 64; ++dd)
    tr[dd] = test[(size_t)m * DDIM + dd * 64 + lane];
#pragma unroll 1
  for (int c = wid; c < C2; c += 4) {
    const float* Tc = trainT + (size_t)selC[c] * DDIM;
    double s = 0.0;
#pragma unroll
    for (int dd = 0; dd < DDIM / 64; ++dd)
      s += (double)tr[dd] * (double)Tc[dd * 64 + lane];
#pragma unroll
    for (int off = 32; off > 0; off >>= 1) s += __shfl_xor(s, off);
    if (lane == 0) rvs[c] = s;
  }
  __syncthreads();

  if (t < C2) {
    double v = rvs[t]; int id = selC[t];
    int r = 0;
    for (int n = 0; n < C2; ++n)
      r += (rvs[n] > v || (rvs[n] == v && selC[n] < id)) ? 1 : 0;
    sv2[r] = v; si2[r] = id;
  }
  __syncthreads();

  if (t < KNN) earr[t] = exp(sv2[t] - sv2[0]);
  __syncthreads();
  if (t < KNN) {
    double ssum = 0.0;
    for (int k = 0; k < KNN; ++k) ssum += earr[k];
    wv[t] = earr[t] / ssum;
    wi[t] = si2[t];
  }
  __syncthreads();

  // ---- per-pixel weighted vote (f64) + argmax ----
  unsigned int packed[5];
#pragma unroll
  for (int q = 0; q < 5; ++q) {
    unsigned int p = 0;
#pragma unroll
    for (int j = 0; j < 4; ++j)
      p |= (unsigned int)labT[(size_t)wi[q * 4 + j] * 256 + t] << (8 * j);
    packed[q] = p;
  }
  double best = -1.0; int bc = 0;
#pragma unroll 1
  for (int c = 0; c < NCLS; ++c) {
    double s = 0.0;
#pragma unroll
    for (int k = 0; k < KNN; ++k) {
      unsigned int lab = (packed[k >> 2] >> ((k & 3) * 8)) & 255u;
      s += (lab == (unsigned int)c) ? wv[k] : 0.0;
    }
    if (s > best) { best = s; bc = c; }
  }
  const int b = m / 196, p = m % 196;
  const int py = p / 14, px = p % 14;
  const int i = t >> 4, j = t & 15;
  out[((size_t)b * 224 + py * 16 + i) * 224 + px * 16 + j] = bc;
}

// ---------------- launch ------------------------------------------------------
// ws layout (bytes), total 139,247,616 (< ~307 MB poisoned ws):
//   labT    @ 0           : 12,800,000
//   Apack   @ 12,800,000  :  1,277,952  (u16 [104][12][64][8])
//   Bpack   @ 14,077,952  : 38,535,168  (u16 [3136][12][64][8])
//   trainT  @ 52,613,120  : 76,800,000  (f32 [50000][384])
//   toplist @ 129,413,120 :  9,834,496  (u32 [1568][1568])
extern "C" void kernel_launch(void* const* d_in, const int* in_sizes, int n_in,
                              void* d_out, int out_size, void* d_ws, size_t ws_size,
                              hipStream_t stream) {
  const float* test  = (const float*)d_in[0];   // [1568][384]
  const float* train = (const float*)d_in[1];   // [384][50000]
  const int* labels  = (const int*)d_in[2];     // [256][50000]
  int* out = (int*)d_out;
  char* ws = (char*)d_ws;

  unsigned char*  labT    = (unsigned char*)ws;
  unsigned short* Apack   = (unsigned short*)(ws + 12800000);
  unsigned short* Bpack   = (unsigned short*)(ws + 14077952);
  float*          trainT  = (float*)(ws + 52613120);
  unsigned int*   toplist = (unsigned int*)(ws + 129413120);

  prep_fused<<<dim3(10328), 256, 0, stream>>>(labels, train, test, labT, Bpack, trainT, Apack);
  mfma_gemm<<<dim3(637), 512, 106496, stream>>>(Apack, Bpack, toplist);
  tail_fused<<<dim3(M_ROWS), 256, 0, stream>>>(toplist, test, trainT, labT, out);
}